// Round 13
// baseline (248.455 us; speedup 1.0000x reference)
//
#include <hip/hip_runtime.h>
#include <hip/hip_fp16.h>
#include <math.h>

#define BB 4
#define NN 2304
#define CC 256
#define HS 48
#define HID 1024
#define BNROWS (BB * NN)                 // 9216
#define ATTN_SCALE 0.17677669529663687f  // 32^-0.5

typedef _Float16 f16;
typedef __attribute__((ext_vector_type(2))) _Float16 h2;
typedef __attribute__((ext_vector_type(8))) _Float16 h8;
typedef __attribute__((ext_vector_type(4))) float f4;

static __device__ __forceinline__ float wave_sum64(float v) {
    v += __shfl_xor(v, 32, 64);
    v += __shfl_xor(v, 16, 64);
    v += __shfl_xor(v, 8, 64);
    v += __shfl_xor(v, 4, 64);
    v += __shfl_xor(v, 2, 64);
    v += __shfl_xor(v, 1, 64);
    return v;
}

// ---------------- merged prep + LN1 ----------------
// blocks 0..767: 32x32 transpose tiles fp32 [K][N] -> f16 [N][K]
// block 768: fused qkv bias; blocks 769+: LN1 (one wave per row), fp32 -> f16
__global__ __launch_bounds__(256) void prep_ln1_kernel(
    const float* __restrict__ x, const float* __restrict__ xkv,
    const float* __restrict__ Wq, const float* __restrict__ Wk,
    const float* __restrict__ Wv, const float* __restrict__ Wp,
    const float* __restrict__ W1, const float* __restrict__ W2,
    const float* __restrict__ bq, const float* __restrict__ bk,
    const float* __restrict__ bv,
    const float* __restrict__ g, const float* __restrict__ be,
    f16* __restrict__ WqkvT, f16* __restrict__ WpT,
    f16* __restrict__ W1T, f16* __restrict__ W2T, float* __restrict__ bqkv,
    f16* __restrict__ hq, f16* __restrict__ hkv)
{
    __shared__ float tt[32][33];
    int bx = blockIdx.x;
    const int tid = threadIdx.x;
    if (bx < 768) {
        const float* src; f16* dst; int K, N;
        if (bx < 64)        { src = Wq; dst = WqkvT;           K = 256;  N = 256; }
        else if (bx < 128)  { src = Wk; dst = WqkvT + 65536;   K = 256;  N = 256;  bx -= 64; }
        else if (bx < 192)  { src = Wv; dst = WqkvT + 131072;  K = 256;  N = 256;  bx -= 128; }
        else if (bx < 256)  { src = Wp; dst = WpT;             K = 256;  N = 256;  bx -= 192; }
        else if (bx < 512)  { src = W1; dst = W1T;             K = 256;  N = 1024; bx -= 256; }
        else                { src = W2; dst = W2T;             K = 1024; N = 256;  bx -= 512; }
        const int tN = N >> 5;
        const int kt = bx / tN, nt = bx - kt * tN;
        const int rr = tid >> 5, cc = tid & 31;
#pragma unroll
        for (int j = 0; j < 4; ++j)
            tt[rr + 8 * j][cc] = src[(size_t)(kt * 32 + rr + 8 * j) * N + nt * 32 + cc];
        __syncthreads();
#pragma unroll
        for (int j = 0; j < 4; ++j)
            dst[(size_t)(nt * 32 + rr + 8 * j) * K + kt * 32 + cc] = (f16)tt[cc][rr + 8 * j];
        return;
    }
    if (bx == 768) {
        if (tid < 256) {
            bqkv[tid]       = bq[tid];
            bqkv[tid + 256] = bk[tid];
            bqkv[tid + 512] = bv[tid];
        }
        return;
    }
    const int r = (bx - 769) * 4 + (tid >> 6);  // 0..2*BNROWS-1
    const int lane = tid & 63;
    const float* src; f16* dst;
    if (r < BNROWS) { src = x + (size_t)r * CC;              dst = hq + (size_t)r * CC; }
    else { src = xkv + (size_t)(r - BNROWS) * CC; dst = hkv + (size_t)(r - BNROWS) * CC; }
    const float4 v = ((const float4*)src)[lane];
    const float mu = wave_sum64(v.x + v.y + v.z + v.w) * (1.0f / CC);
    const float d0 = v.x - mu, d1 = v.y - mu, d2 = v.z - mu, d3 = v.w - mu;
    const float var = wave_sum64(d0 * d0 + d1 * d1 + d2 * d2 + d3 * d3) * (1.0f / CC);
    const float rs = rsqrtf(var + 1e-6f);
    const float4 g4 = ((const float4*)g)[lane];
    const float4 b4 = ((const float4*)be)[lane];
    h2 o01 = (h2){(f16)(d0 * rs * g4.x + b4.x), (f16)(d1 * rs * g4.y + b4.y)};
    h2 o23 = (h2){(f16)(d2 * rs * g4.z + b4.z), (f16)(d3 * rs * g4.w + b4.w)};
    ((h2*)dst)[lane * 2] = o01;
    ((h2*)dst)[lane * 2 + 1] = o23;
}

// ---------------- LDS-free direct-fragment MFMA GEMM ----------------
// Working set is L2-resident, so A/B fragments load straight from global as
// per-lane 16B dwordx4 (frag layouts are 16B-contiguous in [m][k] / [n][k]).
// No LDS, no barriers, no waitcnt hazards; K is a compile-time constant so
// the loop unrolls and the compiler pipelines the independent loads.
// Wave owns a 32(M)x64(N) tile. QKV: A/out selected per n-block.
template <bool GELU, int RESID, bool OUTF32, bool QKV, int KK>
__global__ __launch_bounds__(256) void gemm_direct(
    const f16* __restrict__ Aq, const f16* __restrict__ Akv,
    const f16* __restrict__ Bt, const float* __restrict__ bias,
    const void* __restrict__ resid, void* __restrict__ out1,
    void* __restrict__ outkv, int N)
{
    const int tid = threadIdx.x;
    const int wid = tid >> 6, lane = tid & 63;
    const int ln15 = lane & 15, quad = lane >> 4;
    const int n0 = blockIdx.x * 64;
    const int m0 = (blockIdx.y * 4 + wid) * 32;
    const f16* Ap = QKV ? (n0 < 256 ? Aq : Akv) : Aq;

    const f16* a0p = Ap + (size_t)(m0 + ln15) * KK + quad * 8;
    const f16* a1p = a0p + (size_t)16 * KK;
    const f16* b0p = Bt + (size_t)(n0 + ln15) * KK + quad * 8;

    f4 acc[2][4];
#pragma unroll
    for (int i = 0; i < 2; ++i)
#pragma unroll
        for (int j = 0; j < 4; ++j) acc[i][j] = (f4){0.f, 0.f, 0.f, 0.f};

#pragma unroll 8
    for (int k0 = 0; k0 < KK; k0 += 32) {
        h8 aF[2], bF[4];
        aF[0] = *(const h8*)(a0p + k0);
        aF[1] = *(const h8*)(a1p + k0);
#pragma unroll
        for (int nt = 0; nt < 4; ++nt)
            bF[nt] = *(const h8*)(b0p + (size_t)(nt * 16) * KK + k0);
#pragma unroll
        for (int mt = 0; mt < 2; ++mt)
#pragma unroll
            for (int nt = 0; nt < 4; ++nt)
                acc[mt][nt] = __builtin_amdgcn_mfma_f32_16x16x32_f16(
                    aF[mt], bF[nt], acc[mt][nt], 0, 0, 0);
    }

#pragma unroll
    for (int nt = 0; nt < 4; ++nt) {
        const int gn = n0 + nt * 16 + ln15;
        const float bs = bias[gn];
#pragma unroll
        for (int mt = 0; mt < 2; ++mt) {
#pragma unroll
            for (int r = 0; r < 4; ++r) {
                const int gm = m0 + mt * 16 + quad * 4 + r;
                float v = acc[mt][nt][r] + bs;
                if (GELU) v = 0.5f * v * (1.0f + erff(v * 0.70710678118654752f));
                if (RESID == 1) v += ((const float*)resid)[(size_t)gm * N + gn];
                if (RESID == 2) v += (float)((const f16*)resid)[(size_t)gm * N + gn];
                if (QKV) {
                    if (gn < 256) ((f16*)out1)[(size_t)gm * 256 + gn] = (f16)v;
                    else ((f16*)outkv)[(size_t)gm * 512 + (gn - 256)] = (f16)v;
                } else if (OUTF32) {
                    ((float*)out1)[(size_t)gm * N + gn] = v;
                } else {
                    ((f16*)out1)[(size_t)gm * N + gn] = (f16)v;
                }
            }
        }
    }
}

// ---------------- fused out-projection + residual + LN2 ----------------
// Block = 32 rows x full N=256 (4 waves, one 32x64 n-tile each, direct frags).
// x1 written to global AND mirrored in LDS; after syncthreads each wave
// LayerNorms 8 rows from LDS and writes m2. Saves the ln2 launch.
__global__ __launch_bounds__(256) void proj_ln2_kernel(
    const f16* __restrict__ ao, const f16* __restrict__ WpT,
    const float* __restrict__ bp, const float* __restrict__ xres,
    const float* __restrict__ g, const float* __restrict__ be,
    f16* __restrict__ x1, f16* __restrict__ m2)
{
    __shared__ f16 xt[32][258];   // odd word stride -> conflict-free LN reads
    const int tid = threadIdx.x;
    const int wid = tid >> 6, lane = tid & 63;
    const int ln15 = lane & 15, quad = lane >> 4;
    const int m0 = blockIdx.x * 32;
    const int n0 = wid * 64;

    const f16* a0p = ao + (size_t)(m0 + ln15) * 256 + quad * 8;
    const f16* a1p = a0p + (size_t)16 * 256;
    const f16* b0p = WpT + (size_t)(n0 + ln15) * 256 + quad * 8;

    f4 acc[2][4];
#pragma unroll
    for (int i = 0; i < 2; ++i)
#pragma unroll
        for (int j = 0; j < 4; ++j) acc[i][j] = (f4){0.f, 0.f, 0.f, 0.f};

#pragma unroll
    for (int k0 = 0; k0 < 256; k0 += 32) {
        h8 aF[2], bF[4];
        aF[0] = *(const h8*)(a0p + k0);
        aF[1] = *(const h8*)(a1p + k0);
#pragma unroll
        for (int nt = 0; nt < 4; ++nt)
            bF[nt] = *(const h8*)(b0p + (size_t)(nt * 16) * 256 + k0);
#pragma unroll
        for (int mt = 0; mt < 2; ++mt)
#pragma unroll
            for (int nt = 0; nt < 4; ++nt)
                acc[mt][nt] = __builtin_amdgcn_mfma_f32_16x16x32_f16(
                    aF[mt], bF[nt], acc[mt][nt], 0, 0, 0);
    }

#pragma unroll
    for (int nt = 0; nt < 4; ++nt) {
        const int gn = n0 + nt * 16 + ln15;
        const float bs = bp[gn];
#pragma unroll
        for (int mt = 0; mt < 2; ++mt) {
#pragma unroll
            for (int r = 0; r < 4; ++r) {
                const int gm = m0 + mt * 16 + quad * 4 + r;
                const float v = acc[mt][nt][r] + bs + xres[(size_t)gm * 256 + gn];
                const f16 vh = (f16)v;
                x1[(size_t)gm * 256 + gn] = vh;
                xt[gm - m0][gn] = vh;
            }
        }
    }
    __syncthreads();

    // LN2: wave handles rows wid*8 .. wid*8+7
#pragma unroll 1
    for (int rr = 0; rr < 8; ++rr) {
        const int lr = wid * 8 + rr;
        const f16* src = &xt[lr][lane * 4];
        const float v0 = (float)src[0], v1 = (float)src[1];
        const float v2 = (float)src[2], v3 = (float)src[3];
        const float mu = wave_sum64(v0 + v1 + v2 + v3) * (1.0f / CC);
        const float d0 = v0 - mu, d1 = v1 - mu, d2 = v2 - mu, d3 = v3 - mu;
        const float var = wave_sum64(d0 * d0 + d1 * d1 + d2 * d2 + d3 * d3) * (1.0f / CC);
        const float rs = rsqrtf(var + 1e-6f);
        const float4 g4 = ((const float4*)g)[lane];
        const float4 b4 = ((const float4*)be)[lane];
        f16* dst = m2 + (size_t)(m0 + lr) * CC;
        h2 o01 = (h2){(f16)(d0 * rs * g4.x + b4.x), (f16)(d1 * rs * g4.y + b4.y)};
        h2 o23 = (h2){(f16)(d2 * rs * g4.z + b4.z), (f16)(d3 * rs * g4.w + b4.w)};
        ((h2*)dst)[lane * 2] = o01;
        ((h2*)dst)[lane * 2 + 1] = o23;
    }
}

// ---------------- tiled sparse spatial attention (r12-proven) ----------------
// exp(-1e9-m)==0 in fp32 so only in-radius keys contribute (== reference).
__device__ __constant__ int ATT_DY[29] = {
    -3, -2, -2, -2, -2, -2, -1, -1, -1, -1, -1, 0, 0, 0, 0,
    0, 0, 0, 1, 1, 1, 1, 1, 2, 2, 2, 2, 2, 3};
__device__ __constant__ int ATT_DX[29] = {
    0, -2, -1, 0, 1, 2, -2, -1, 0, 1, 2, -3, -2, -1, 0,
    1, 2, 3, -2, -1, 0, 1, 2, -2, -1, 0, 1, 2, 0};

__global__ __launch_bounds__(128) void attn_tile_kernel(
    const f16* __restrict__ qf, const f16* __restrict__ kvf,
    f16* __restrict__ ao)
{
    __shared__ f16 ks[196][66];
    __shared__ f16 vs[196][66];
    const int tile = blockIdx.x, hp = blockIdx.y, b = blockIdx.z;
    const int ty0 = (tile / 6) * 8, tx0 = (tile - (tile / 6) * 6) * 8;
    const int tid = threadIdx.x;

    for (int idx = tid; idx < 196 * 16; idx += 128) {
        const int r = idx >> 4, seg = idx & 15;
        const int gy = ty0 - 3 + r / 14, gx = tx0 - 3 + (r - (r / 14) * 14);
        uint4 val = {0u, 0u, 0u, 0u};
        if ((unsigned)gy < HS && (unsigned)gx < HS) {
            const size_t rowb = ((size_t)b * NN + gy * HS + gx) * 512;
            const int ch = (seg < 8) ? (hp * 64 + seg * 8)
                                     : (256 + hp * 64 + (seg - 8) * 8);
            val = *(const uint4*)&kvf[rowb + ch];
        }
        f16* dstp = (seg < 8) ? &ks[r][(seg & 7) * 8] : &vs[r][(seg & 7) * 8];
        ((unsigned int*)dstp)[0] = val.x;
        ((unsigned int*)dstp)[1] = val.y;
        ((unsigned int*)dstp)[2] = val.z;
        ((unsigned int*)dstp)[3] = val.w;
    }
    __syncthreads();

    const int q = tid & 63, hh = tid >> 6;
    const int qy = q >> 3, qx = q & 7;
    const size_t qrow = (size_t)b * NN + (ty0 + qy) * HS + tx0 + qx;
    const f16* qp = qf + qrow * CC + hp * 64 + hh * 32;
    uint4 qa[4];
#pragma unroll
    for (int i = 0; i < 4; ++i) qa[i] = ((const uint4*)qp)[i];
    const h2* q2 = (const h2*)qa;

    float s[29];
#pragma unroll
    for (int n = 0; n < 29; ++n) {
        const int dy = ATT_DY[n], dx = ATT_DX[n];
        const int r = (qy + 3 + dy) * 14 + qx + 3 + dx;
        const bool valid = (unsigned)(ty0 + qy + dy) < HS &&
                           (unsigned)(tx0 + qx + dx) < HS;
        float a = 0.0f;
        const h2* kp = (const h2*)&ks[r][hh * 32];
#pragma unroll
        for (int i = 0; i < 16; ++i)
            a = __builtin_amdgcn_fdot2(q2[i], kp[i], a, false);
        s[n] = valid ? a * ATTN_SCALE : -1e30f;
    }
    float m = s[0];
#pragma unroll
    for (int n = 1; n < 29; ++n) m = fmaxf(m, s[n]);
    float l = 0.0f;
#pragma unroll
    for (int n = 0; n < 29; ++n) { s[n] = __expf(s[n] - m); l += s[n]; }
    h2 a2[16];
#pragma unroll
    for (int i = 0; i < 16; ++i) a2[i] = (h2){(f16)0.f, (f16)0.f};
#pragma unroll
    for (int n = 0; n < 29; ++n) {
        const int dy = ATT_DY[n], dx = ATT_DX[n];
        const int r = (qy + 3 + dy) * 14 + qx + 3 + dx;
        const f16 pn = (f16)s[n];
        const h2 ph = (h2){pn, pn};
        const h2* vp = (const h2*)&vs[r][hh * 32];
#pragma unroll
        for (int i = 0; i < 16; ++i) a2[i] += ph * vp[i];
    }
    const float inv = 1.0f / l;
    uint4 ov[4];
    f16* oh = (f16*)ov;
#pragma unroll
    for (int i = 0; i < 16; ++i) {
        oh[2 * i]     = (f16)((float)a2[i][0] * inv);
        oh[2 * i + 1] = (f16)((float)a2[i][1] * inv);
    }
    uint4* dst = (uint4*)(ao + qrow * CC + hp * 64 + hh * 32);
#pragma unroll
    for (int i = 0; i < 4; ++i) dst[i] = ov[i];
}

extern "C" void kernel_launch(void* const* d_in, const int* in_sizes, int n_in,
                              void* d_out, int out_size, void* d_ws, size_t ws_size,
                              hipStream_t stream) {
    const float* x    = (const float*)d_in[0];
    const float* x_kv = (const float*)d_in[1];
    const float* Wq   = (const float*)d_in[2];
    const float* bq   = (const float*)d_in[3];
    const float* Wk   = (const float*)d_in[4];
    const float* bk   = (const float*)d_in[5];
    const float* Wv   = (const float*)d_in[6];
    const float* bv   = (const float*)d_in[7];
    const float* Wp   = (const float*)d_in[8];
    const float* bp   = (const float*)d_in[9];
    const float* g1   = (const float*)d_in[10];
    const float* b1   = (const float*)d_in[11];
    const float* g2   = (const float*)d_in[12];
    const float* b2   = (const float*)d_in[13];
    const float* W1   = (const float*)d_in[14];
    const float* bm1  = (const float*)d_in[15];
    const float* W2   = (const float*)d_in[16];
    const float* bm2  = (const float*)d_in[17];
    float* outp = (float*)d_out;   // fp32 output (verified)

    // ws layout (f16 element offsets); overlays by stream-ordered lifetime:
    //   ao over hq (dead after qkv); x1 over hkv (dead after qkv);
    //   m2 over qf (dead after attn); hidF over kvf.. (dead after attn).
    f16* wsh = (f16*)d_ws;
    f16* WqkvT = wsh;                      // 196608
    f16* WpT   = wsh + 196608;             // 65536
    f16* W1T   = wsh + 262144;             // 262144
    f16* W2T   = wsh + 524288;             // 262144
    float* bqkv = (float*)(wsh + 786432);  // 768 fp32
    f16* hq    = wsh + 787968;             // 2359296
    f16* hkv   = wsh + 3147264;            // 2359296
    f16* qf    = wsh + 5506560;            // 2359296
    f16* kvf   = wsh + 7865856;            // 4718592 (end 12584448)
    f16* ao    = hq;
    f16* x1    = hkv;
    f16* m2    = qf;
    f16* hidF  = kvf;                      // 9437184 -> end 17303040 (34.6 MB)
    const bool fused = ws_size >= (size_t)17303040 * sizeof(f16);

    // 1. merged weight prep + LN1
    prep_ln1_kernel<<<5377, 256, 0, stream>>>(
        x, x_kv, Wq, Wk, Wv, Wp, W1, W2, bq, bk, bv, g1, b1,
        WqkvT, WpT, W1T, W2T, bqkv, hq, hkv);
    // 2. fused Q|K|V projection (tiles 288(M) x 12(N))
    gemm_direct<false, 0, false, true, 256><<<dim3(12, 72), 256, 0, stream>>>(
        hq, hkv, WqkvT, bqkv, nullptr, qf, kvf, 768);
    // 3. attention
    attn_tile_kernel<<<dim3(36, 4, BB), 128, 0, stream>>>(qf, kvf, ao);
    // 4. out-proj + residual + LN2 (one kernel)
    proj_ln2_kernel<<<288, 256, 0, stream>>>(ao, WpT, bp, x, g2, b2, x1, m2);
    // 5/6. MLP
    if (fused) {
        gemm_direct<true, 0, false, false, 256><<<dim3(16, 72), 256, 0, stream>>>(
            m2, nullptr, W1T, bm1, nullptr, hidF, nullptr, 1024);
        gemm_direct<false, 2, true, false, 1024><<<dim3(4, 72), 256, 0, stream>>>(
            hidF, nullptr, W2T, bm2, x1, outp, nullptr, 256);
    } else {
        for (int b = 0; b < BB; ++b) {
            const size_t off = (size_t)b * NN * CC;
            gemm_direct<true, 0, false, false, 256><<<dim3(16, 18), 256, 0, stream>>>(
                m2 + off, nullptr, W1T, bm1, nullptr, hidF, nullptr, 1024);
            gemm_direct<false, 2, true, false, 1024><<<dim3(4, 18), 256, 0, stream>>>(
                hidF, nullptr, W2T, bm2, x1 + off, outp + off, nullptr, 256);
        }
    }
    (void)in_sizes; (void)n_in; (void)out_size;
}

// Round 14
// 226.576 us; speedup vs baseline: 1.0966x; 1.0966x over previous
//
#include <hip/hip_runtime.h>
#include <hip/hip_fp16.h>
#include <math.h>

#define BB 4
#define NN 2304
#define CC 256
#define HS 48
#define HID 1024
#define BNROWS (BB * NN)                 // 9216
#define ATTN_SCALE 0.17677669529663687f  // 32^-0.5

typedef _Float16 f16;
typedef __attribute__((ext_vector_type(2))) _Float16 h2;
typedef __attribute__((ext_vector_type(8))) _Float16 h8;
typedef __attribute__((ext_vector_type(4))) float f4;

#define GLLS16(g, l)                                                        \
    __builtin_amdgcn_global_load_lds(                                       \
        (const __attribute__((address_space(1))) unsigned int*)(g),         \
        (__attribute__((address_space(3))) unsigned int*)(l), 16, 0, 0)
#define WAIT_VM0()   asm volatile("s_waitcnt vmcnt(0)" ::: "memory")
#define WAIT_VM6()   asm volatile("s_waitcnt vmcnt(6)" ::: "memory")
#define WAIT_LGKM0() asm volatile("s_waitcnt lgkmcnt(0)" ::: "memory")

static __device__ __forceinline__ float wave_sum64(float v) {
    v += __shfl_xor(v, 32, 64);
    v += __shfl_xor(v, 16, 64);
    v += __shfl_xor(v, 8, 64);
    v += __shfl_xor(v, 4, 64);
    v += __shfl_xor(v, 2, 64);
    v += __shfl_xor(v, 1, 64);
    return v;
}

// ---------------- merged prep + LN1 (r12-proven) ----------------
__global__ __launch_bounds__(256) void prep_ln1_kernel(
    const float* __restrict__ x, const float* __restrict__ xkv,
    const float* __restrict__ Wq, const float* __restrict__ Wk,
    const float* __restrict__ Wv, const float* __restrict__ Wp,
    const float* __restrict__ W1, const float* __restrict__ W2,
    const float* __restrict__ bq, const float* __restrict__ bk,
    const float* __restrict__ bv,
    const float* __restrict__ g, const float* __restrict__ be,
    f16* __restrict__ WqkvT, f16* __restrict__ WpT,
    f16* __restrict__ W1T, f16* __restrict__ W2T, float* __restrict__ bqkv,
    f16* __restrict__ hq, f16* __restrict__ hkv)
{
    __shared__ float tt[32][33];
    int bx = blockIdx.x;
    const int tid = threadIdx.x;
    if (bx < 768) {
        const float* src; f16* dst; int K, N;
        if (bx < 64)        { src = Wq; dst = WqkvT;           K = 256;  N = 256; }
        else if (bx < 128)  { src = Wk; dst = WqkvT + 65536;   K = 256;  N = 256;  bx -= 64; }
        else if (bx < 192)  { src = Wv; dst = WqkvT + 131072;  K = 256;  N = 256;  bx -= 128; }
        else if (bx < 256)  { src = Wp; dst = WpT;             K = 256;  N = 256;  bx -= 192; }
        else if (bx < 512)  { src = W1; dst = W1T;             K = 256;  N = 1024; bx -= 256; }
        else                { src = W2; dst = W2T;             K = 1024; N = 256;  bx -= 512; }
        const int tN = N >> 5;
        const int kt = bx / tN, nt = bx - kt * tN;
        const int rr = tid >> 5, cc = tid & 31;
#pragma unroll
        for (int j = 0; j < 4; ++j)
            tt[rr + 8 * j][cc] = src[(size_t)(kt * 32 + rr + 8 * j) * N + nt * 32 + cc];
        __syncthreads();
#pragma unroll
        for (int j = 0; j < 4; ++j)
            dst[(size_t)(nt * 32 + rr + 8 * j) * K + kt * 32 + cc] = (f16)tt[cc][rr + 8 * j];
        return;
    }
    if (bx == 768) {
        if (tid < 256) {
            bqkv[tid]       = bq[tid];
            bqkv[tid + 256] = bk[tid];
            bqkv[tid + 512] = bv[tid];
        }
        return;
    }
    const int r = (bx - 769) * 4 + (tid >> 6);  // 0..2*BNROWS-1
    const int lane = tid & 63;
    const float* src; f16* dst;
    if (r < BNROWS) { src = x + (size_t)r * CC;              dst = hq + (size_t)r * CC; }
    else { src = xkv + (size_t)(r - BNROWS) * CC; dst = hkv + (size_t)(r - BNROWS) * CC; }
    const float4 v = ((const float4*)src)[lane];
    const float mu = wave_sum64(v.x + v.y + v.z + v.w) * (1.0f / CC);
    const float d0 = v.x - mu, d1 = v.y - mu, d2 = v.z - mu, d3 = v.w - mu;
    const float var = wave_sum64(d0 * d0 + d1 * d1 + d2 * d2 + d3 * d3) * (1.0f / CC);
    const float rs = rsqrtf(var + 1e-6f);
    const float4 g4 = ((const float4*)g)[lane];
    const float4 b4 = ((const float4*)be)[lane];
    h2 o01 = (h2){(f16)(d0 * rs * g4.x + b4.x), (f16)(d1 * rs * g4.y + b4.y)};
    h2 o23 = (h2){(f16)(d2 * rs * g4.z + b4.z), (f16)(d3 * rs * g4.w + b4.w)};
    ((h2*)dst)[lane * 2] = o01;
    ((h2*)dst)[lane * 2 + 1] = o23;
}

// ---------------- wave-autonomous MFMA GEMM, double-buffered (r12) ----------
// Used for QKV only. Wave owns 32(M)x64(N); two private LDS buffers; glls
// staging; vmcnt(6) drains only the current buffer's 6 loads.
__global__ __launch_bounds__(256, 4) void gemm_qkv(
    const f16* __restrict__ Aq, const f16* __restrict__ Akv,
    const f16* __restrict__ Bt, const float* __restrict__ bias,
    f16* __restrict__ qf, f16* __restrict__ kvf)
{
    __shared__ f16 lds[4 * 6144];
    const int tid = threadIdx.x;
    const int wid = tid >> 6, lane = tid & 63;
    const int ln15 = lane & 15, quad = lane >> 4;
    const int jr = lane >> 2, js = lane & 3;
    f16* slot = lds + wid * 6144;
    const int n0 = blockIdx.x * 64;
    const int m0 = (blockIdx.y * 4 + wid) * 32;
    const f16* Ap = (n0 < 256) ? Aq : Akv;
    const int K = 256;

    size_t ga[2], gb[4];
#pragma unroll
    for (int i = 0; i < 2; ++i) {
        const int r = i * 16 + jr;
        const int q = (js - (r >> 1)) & 3;
        ga[i] = (size_t)(m0 + r) * K + q * 8;
    }
#pragma unroll
    for (int i = 0; i < 4; ++i) {
        const int r = i * 16 + jr;
        const int q = (js - (r >> 1)) & 3;
        gb[i] = (size_t)(n0 + r) * K + q * 8;
    }
    int aoff[2], boff[4];
#pragma unroll
    for (int mt = 0; mt < 2; ++mt) {
        const int r = mt * 16 + ln15;
        aoff[mt] = (r * 4 + ((quad + (r >> 1)) & 3)) * 16;
    }
#pragma unroll
    for (int nt = 0; nt < 4; ++nt) {
        const int r = nt * 16 + ln15;
        boff[nt] = (r * 4 + ((quad + (r >> 1)) & 3)) * 16;
    }

    f4 acc[2][4];
#pragma unroll
    for (int i = 0; i < 2; ++i)
#pragma unroll
        for (int j = 0; j < 4; ++j) acc[i][j] = (f4){0.f, 0.f, 0.f, 0.f};

    {
        f16* Al = slot;
        f16* Bl = slot + 1024;
#pragma unroll
        for (int i = 0; i < 2; ++i) GLLS16(Ap + ga[i], Al + i * 512);
#pragma unroll
        for (int i = 0; i < 4; ++i) GLLS16(Bt + gb[i], Bl + i * 512);
    }
    int cur = 0;
    for (int k0 = 0; k0 < K; k0 += 32) {
        const bool more = (k0 + 32 < K);
        f16* Ac = slot + cur * 3072;
        f16* Bc = Ac + 1024;
        if (more) {
            f16* An = slot + (cur ^ 1) * 3072;
            f16* Bn = An + 1024;
            WAIT_LGKM0();
#pragma unroll
            for (int i = 0; i < 2; ++i) GLLS16(Ap + ga[i] + k0 + 32, An + i * 512);
#pragma unroll
            for (int i = 0; i < 4; ++i) GLLS16(Bt + gb[i] + k0 + 32, Bn + i * 512);
            WAIT_VM6();
        } else {
            WAIT_VM0();
        }
        h8 aF[2], bF[4];
#pragma unroll
        for (int nt = 0; nt < 4; ++nt)
            bF[nt] = *(const h8*)((const char*)Bc + boff[nt]);
#pragma unroll
        for (int mt = 0; mt < 2; ++mt)
            aF[mt] = *(const h8*)((const char*)Ac + aoff[mt]);
#pragma unroll
        for (int mt = 0; mt < 2; ++mt)
#pragma unroll
            for (int nt = 0; nt < 4; ++nt)
                acc[mt][nt] = __builtin_amdgcn_mfma_f32_16x16x32_f16(
                    aF[mt], bF[nt], acc[mt][nt], 0, 0, 0);
        cur ^= 1;
    }

#pragma unroll
    for (int nt = 0; nt < 4; ++nt) {
        const int gn = n0 + nt * 16 + ln15;
        const float bs = bias[gn];
#pragma unroll
        for (int mt = 0; mt < 2; ++mt) {
#pragma unroll
            for (int r = 0; r < 4; ++r) {
                const int gm = m0 + mt * 16 + quad * 4 + r;
                const float v = acc[mt][nt][r] + bs;
                if (gn < 256) qf[(size_t)gm * 256 + gn] = (f16)v;
                else kvf[(size_t)gm * 512 + (gn - 256)] = (f16)v;
            }
        }
    }
}

// ---------------- fused out-projection + residual + LN2 (r13-proven) --------
__global__ __launch_bounds__(256) void proj_ln2_kernel(
    const f16* __restrict__ ao, const f16* __restrict__ WpT,
    const float* __restrict__ bp, const float* __restrict__ xres,
    const float* __restrict__ g, const float* __restrict__ be,
    f16* __restrict__ x1, f16* __restrict__ m2)
{
    __shared__ f16 xt[32][258];
    const int tid = threadIdx.x;
    const int wid = tid >> 6, lane = tid & 63;
    const int ln15 = lane & 15, quad = lane >> 4;
    const int m0 = blockIdx.x * 32;
    const int n0 = wid * 64;

    const f16* a0p = ao + (size_t)(m0 + ln15) * 256 + quad * 8;
    const f16* a1p = a0p + (size_t)16 * 256;
    const f16* b0p = WpT + (size_t)(n0 + ln15) * 256 + quad * 8;

    f4 acc[2][4];
#pragma unroll
    for (int i = 0; i < 2; ++i)
#pragma unroll
        for (int j = 0; j < 4; ++j) acc[i][j] = (f4){0.f, 0.f, 0.f, 0.f};
#pragma unroll
    for (int k0 = 0; k0 < 256; k0 += 32) {
        h8 aF[2], bF[4];
        aF[0] = *(const h8*)(a0p + k0);
        aF[1] = *(const h8*)(a1p + k0);
#pragma unroll
        for (int nt = 0; nt < 4; ++nt)
            bF[nt] = *(const h8*)(b0p + (size_t)(nt * 16) * 256 + k0);
#pragma unroll
        for (int mt = 0; mt < 2; ++mt)
#pragma unroll
            for (int nt = 0; nt < 4; ++nt)
                acc[mt][nt] = __builtin_amdgcn_mfma_f32_16x16x32_f16(
                    aF[mt], bF[nt], acc[mt][nt], 0, 0, 0);
    }
#pragma unroll
    for (int nt = 0; nt < 4; ++nt) {
        const int gn = n0 + nt * 16 + ln15;
        const float bs = bp[gn];
#pragma unroll
        for (int mt = 0; mt < 2; ++mt) {
#pragma unroll
            for (int r = 0; r < 4; ++r) {
                const int gm = m0 + mt * 16 + quad * 4 + r;
                const float v = acc[mt][nt][r] + bs + xres[(size_t)gm * 256 + gn];
                const f16 vh = (f16)v;
                x1[(size_t)gm * 256 + gn] = vh;
                xt[gm - m0][gn] = vh;
            }
        }
    }
    __syncthreads();
#pragma unroll 1
    for (int rr = 0; rr < 8; ++rr) {
        const int lr = wid * 8 + rr;
        const f16* src = &xt[lr][lane * 4];
        const float v0 = (float)src[0], v1 = (float)src[1];
        const float v2 = (float)src[2], v3 = (float)src[3];
        const float mu = wave_sum64(v0 + v1 + v2 + v3) * (1.0f / CC);
        const float d0 = v0 - mu, d1 = v1 - mu, d2 = v2 - mu, d3 = v3 - mu;
        const float var = wave_sum64(d0 * d0 + d1 * d1 + d2 * d2 + d3 * d3) * (1.0f / CC);
        const float rs = rsqrtf(var + 1e-6f);
        const float4 g4 = ((const float4*)g)[lane];
        const float4 b4 = ((const float4*)be)[lane];
        f16* dst = m2 + (size_t)(m0 + lr) * CC;
        h2 o01 = (h2){(f16)(d0 * rs * g4.x + b4.x), (f16)(d1 * rs * g4.y + b4.y)};
        h2 o23 = (h2){(f16)(d2 * rs * g4.z + b4.z), (f16)(d3 * rs * g4.w + b4.w)};
        ((h2*)dst)[lane * 2] = o01;
        ((h2*)dst)[lane * 2 + 1] = o23;
    }
}

// ---------------- fused MLP: hid lives only in LDS ----------------
// Block = 32 rows. Phase 1: wave w computes hid[32][w*256..w*256+256) (GELU)
// into LDS with XOR chunk swizzle (chunk ^= row&7 -> phase-2 ds_read_b128 is
// 2-way, free). Phase 2: wave w computes out n-tile [w*64, w*64+64) over
// K=1024 from LDS A-frags + global W2T B-frags; + x1 residual, fp32 store.
__global__ __launch_bounds__(256) void mlp_fused_kernel(
    const f16* __restrict__ m2, const f16* __restrict__ W1T,
    const f16* __restrict__ W2T, const float* __restrict__ bm1,
    const float* __restrict__ bm2, const f16* __restrict__ x1,
    float* __restrict__ outp)
{
    __shared__ f16 hid[32 * 1024];   // 64 KB, swizzled [row][col]
    const int tid = threadIdx.x;
    const int wid = tid >> 6, lane = tid & 63;
    const int ln15 = lane & 15, quad = lane >> 4;
    const int m0 = blockIdx.x * 32;

    // phase 1
    const f16* a0p = m2 + (size_t)(m0 + ln15) * 256 + quad * 8;
    const f16* a1p = a0p + (size_t)16 * 256;
#pragma unroll 1
    for (int nt4 = 0; nt4 < 4; ++nt4) {
        const int n0 = wid * 256 + nt4 * 64;
        const f16* b0p = W1T + (size_t)(n0 + ln15) * 256 + quad * 8;
        f4 acc[2][4];
#pragma unroll
        for (int i = 0; i < 2; ++i)
#pragma unroll
            for (int j = 0; j < 4; ++j) acc[i][j] = (f4){0.f, 0.f, 0.f, 0.f};
#pragma unroll
        for (int k0 = 0; k0 < 256; k0 += 32) {
            h8 aF[2], bF[4];
            aF[0] = *(const h8*)(a0p + k0);
            aF[1] = *(const h8*)(a1p + k0);
#pragma unroll
            for (int nt = 0; nt < 4; ++nt)
                bF[nt] = *(const h8*)(b0p + (size_t)(nt * 16) * 256 + k0);
#pragma unroll
            for (int mt = 0; mt < 2; ++mt)
#pragma unroll
                for (int nt = 0; nt < 4; ++nt)
                    acc[mt][nt] = __builtin_amdgcn_mfma_f32_16x16x32_f16(
                        aF[mt], bF[nt], acc[mt][nt], 0, 0, 0);
        }
#pragma unroll
        for (int nt = 0; nt < 4; ++nt) {
            const int gn = n0 + nt * 16 + ln15;
            const float bs = bm1[gn];
#pragma unroll
            for (int mt = 0; mt < 2; ++mt) {
#pragma unroll
                for (int r = 0; r < 4; ++r) {
                    const int row = mt * 16 + quad * 4 + r;
                    float v = acc[mt][nt][r] + bs;
                    v = 0.5f * v * (1.0f + erff(v * 0.70710678118654752f));
                    const int sc = (gn & 7) | ((((gn >> 3) ^ (row & 7)) & 127) << 3);
                    hid[row * 1024 + sc] = (f16)v;
                }
            }
        }
    }
    __syncthreads();

    // phase 2
    const int n0 = wid * 64;
    const f16* b0p = W2T + (size_t)(n0 + ln15) * 1024 + quad * 8;
    f4 acc[2][4];
#pragma unroll
    for (int i = 0; i < 2; ++i)
#pragma unroll
        for (int j = 0; j < 4; ++j) acc[i][j] = (f4){0.f, 0.f, 0.f, 0.f};
#pragma unroll 8
    for (int k0 = 0; k0 < 1024; k0 += 32) {
        const int ch = (k0 >> 3) + quad;      // chunk index 0..127
        h8 aF[2], bF[4];
        {
            const int r0 = ln15;
            aF[0] = *(const h8*)&hid[r0 * 1024 + ((ch ^ (r0 & 7)) << 3)];
            const int r1 = 16 + ln15;
            aF[1] = *(const h8*)&hid[r1 * 1024 + ((ch ^ (r1 & 7)) << 3)];
        }
#pragma unroll
        for (int nt = 0; nt < 4; ++nt)
            bF[nt] = *(const h8*)(b0p + (size_t)(nt * 16) * 1024 + k0);
#pragma unroll
        for (int mt = 0; mt < 2; ++mt)
#pragma unroll
            for (int nt = 0; nt < 4; ++nt)
                acc[mt][nt] = __builtin_amdgcn_mfma_f32_16x16x32_f16(
                    aF[mt], bF[nt], acc[mt][nt], 0, 0, 0);
    }
#pragma unroll
    for (int nt = 0; nt < 4; ++nt) {
        const int gn = n0 + nt * 16 + ln15;
        const float bs = bm2[gn];
#pragma unroll
        for (int mt = 0; mt < 2; ++mt) {
#pragma unroll
            for (int r = 0; r < 4; ++r) {
                const int gm = m0 + mt * 16 + quad * 4 + r;
                outp[(size_t)gm * 256 + gn] =
                    acc[mt][nt][r] + bs + (float)x1[(size_t)gm * 256 + gn];
            }
        }
    }
}

// ---------------- tiled sparse spatial attention (proven) ----------------
// exp(-1e9-m)==0 in fp32 so only in-radius keys contribute (== reference).
__device__ __constant__ int ATT_DY[29] = {
    -3, -2, -2, -2, -2, -2, -1, -1, -1, -1, -1, 0, 0, 0, 0,
    0, 0, 0, 1, 1, 1, 1, 1, 2, 2, 2, 2, 2, 3};
__device__ __constant__ int ATT_DX[29] = {
    0, -2, -1, 0, 1, 2, -2, -1, 0, 1, 2, -3, -2, -1, 0,
    1, 2, 3, -2, -1, 0, 1, 2, -2, -1, 0, 1, 2, 0};

__global__ __launch_bounds__(128) void attn_tile_kernel(
    const f16* __restrict__ qf, const f16* __restrict__ kvf,
    f16* __restrict__ ao)
{
    __shared__ f16 ks[196][66];
    __shared__ f16 vs[196][66];
    const int tile = blockIdx.x, hp = blockIdx.y, b = blockIdx.z;
    const int ty0 = (tile / 6) * 8, tx0 = (tile - (tile / 6) * 6) * 8;
    const int tid = threadIdx.x;

    for (int idx = tid; idx < 196 * 16; idx += 128) {
        const int r = idx >> 4, seg = idx & 15;
        const int gy = ty0 - 3 + r / 14, gx = tx0 - 3 + (r - (r / 14) * 14);
        uint4 val = {0u, 0u, 0u, 0u};
        if ((unsigned)gy < HS && (unsigned)gx < HS) {
            const size_t rowb = ((size_t)b * NN + gy * HS + gx) * 512;
            const int ch = (seg < 8) ? (hp * 64 + seg * 8)
                                     : (256 + hp * 64 + (seg - 8) * 8);
            val = *(const uint4*)&kvf[rowb + ch];
        }
        f16* dstp = (seg < 8) ? &ks[r][(seg & 7) * 8] : &vs[r][(seg & 7) * 8];
        ((unsigned int*)dstp)[0] = val.x;
        ((unsigned int*)dstp)[1] = val.y;
        ((unsigned int*)dstp)[2] = val.z;
        ((unsigned int*)dstp)[3] = val.w;
    }
    __syncthreads();

    const int q = tid & 63, hh = tid >> 6;
    const int qy = q >> 3, qx = q & 7;
    const size_t qrow = (size_t)b * NN + (ty0 + qy) * HS + tx0 + qx;
    const f16* qp = qf + qrow * CC + hp * 64 + hh * 32;
    uint4 qa[4];
#pragma unroll
    for (int i = 0; i < 4; ++i) qa[i] = ((const uint4*)qp)[i];
    const h2* q2 = (const h2*)qa;

    float s[29];
#pragma unroll
    for (int n = 0; n < 29; ++n) {
        const int dy = ATT_DY[n], dx = ATT_DX[n];
        const int r = (qy + 3 + dy) * 14 + qx + 3 + dx;
        const bool valid = (unsigned)(ty0 + qy + dy) < HS &&
                           (unsigned)(tx0 + qx + dx) < HS;
        float a = 0.0f;
        const h2* kp = (const h2*)&ks[r][hh * 32];
#pragma unroll
        for (int i = 0; i < 16; ++i)
            a = __builtin_amdgcn_fdot2(q2[i], kp[i], a, false);
        s[n] = valid ? a * ATTN_SCALE : -1e30f;
    }
    float m = s[0];
#pragma unroll
    for (int n = 1; n < 29; ++n) m = fmaxf(m, s[n]);
    float l = 0.0f;
#pragma unroll
    for (int n = 0; n < 29; ++n) { s[n] = __expf(s[n] - m); l += s[n]; }
    h2 a2[16];
#pragma unroll
    for (int i = 0; i < 16; ++i) a2[i] = (h2){(f16)0.f, (f16)0.f};
#pragma unroll
    for (int n = 0; n < 29; ++n) {
        const int dy = ATT_DY[n], dx = ATT_DX[n];
        const int r = (qy + 3 + dy) * 14 + qx + 3 + dx;
        const f16 pn = (f16)s[n];
        const h2 ph = (h2){pn, pn};
        const h2* vp = (const h2*)&vs[r][hh * 32];
#pragma unroll
        for (int i = 0; i < 16; ++i) a2[i] += ph * vp[i];
    }
    const float inv = 1.0f / l;
    uint4 ov[4];
    f16* oh = (f16*)ov;
#pragma unroll
    for (int i = 0; i < 16; ++i) {
        oh[2 * i]     = (f16)((float)a2[i][0] * inv);
        oh[2 * i + 1] = (f16)((float)a2[i][1] * inv);
    }
    uint4* dst = (uint4*)(ao + qrow * CC + hp * 64 + hh * 32);
#pragma unroll
    for (int i = 0; i < 4; ++i) dst[i] = ov[i];
}

extern "C" void kernel_launch(void* const* d_in, const int* in_sizes, int n_in,
                              void* d_out, int out_size, void* d_ws, size_t ws_size,
                              hipStream_t stream) {
    const float* x    = (const float*)d_in[0];
    const float* x_kv = (const float*)d_in[1];
    const float* Wq   = (const float*)d_in[2];
    const float* bq   = (const float*)d_in[3];
    const float* Wk   = (const float*)d_in[4];
    const float* bk   = (const float*)d_in[5];
    const float* Wv   = (const float*)d_in[6];
    const float* bv   = (const float*)d_in[7];
    const float* Wp   = (const float*)d_in[8];
    const float* bp   = (const float*)d_in[9];
    const float* g1   = (const float*)d_in[10];
    const float* b1   = (const float*)d_in[11];
    const float* g2   = (const float*)d_in[12];
    const float* b2   = (const float*)d_in[13];
    const float* W1   = (const float*)d_in[14];
    const float* bm1  = (const float*)d_in[15];
    const float* W2   = (const float*)d_in[16];
    const float* bm2  = (const float*)d_in[17];
    float* outp = (float*)d_out;   // fp32 output (verified)

    // ws layout; overlays by stream-ordered lifetime:
    //   ao over hq; x1 over hkv; m2 over qf.
    f16* wsh = (f16*)d_ws;
    f16* WqkvT = wsh;                      // 196608
    f16* WpT   = wsh + 196608;             // 65536
    f16* W1T   = wsh + 262144;             // 262144
    f16* W2T   = wsh + 524288;             // 262144
    float* bqkv = (float*)(wsh + 786432);  // 768 fp32
    f16* hq    = wsh + 787968;             // 2359296
    f16* hkv   = wsh + 3147264;            // 2359296
    f16* qf    = wsh + 5506560;            // 2359296
    f16* kvf   = wsh + 7865856;            // 4718592
    f16* ao    = hq;
    f16* x1    = hkv;
    f16* m2    = qf;

    // 1. merged weight prep + LN1
    prep_ln1_kernel<<<5377, 256, 0, stream>>>(
        x, x_kv, Wq, Wk, Wv, Wp, W1, W2, bq, bk, bv, g1, b1,
        WqkvT, WpT, W1T, W2T, bqkv, hq, hkv);
    // 2. fused Q|K|V projection
    gemm_qkv<<<dim3(12, 72), 256, 0, stream>>>(hq, hkv, WqkvT, bqkv, qf, kvf);
    // 3. attention
    attn_tile_kernel<<<dim3(36, 4, BB), 128, 0, stream>>>(qf, kvf, ao);
    // 4. out-proj + residual + LN2
    proj_ln2_kernel<<<288, 256, 0, stream>>>(ao, WpT, bp, x, g2, b2, x1, m2);
    // 5. fused MLP (hid in LDS only)
    mlp_fused_kernel<<<288, 256, 0, stream>>>(m2, W1T, W2T, bm1, bm2, x1, outp);
    (void)in_sizes; (void)n_in; (void)out_size; (void)ws_size;
}